// Round 10
// baseline (736.449 us; speedup 1.0000x reference)
//
#include <hip/hip_runtime.h>

// Chamfer distance via exact two-level uniform-grid NN search.
// FINE grid 64^3, h=0.1, box [-3.2,3.2] (clamped; exact: edge cells are
// open-ended in the finality bound, clamped points are extra candidates).
// COARSE grid 32^3, h2=0.4, box [-6.4,6.4] (all points interior).
// Pass1 (thread/query, dirs fused): fine 27-cell scan; final iff
// best <= bound^2 (exact distance to unscanned region). Else worklist.
// Pass2 (wave/query, static interleave): ONE-SHOT coarse box scan with
// radius derived from the pass1 seed (Rb*H2 >= sqrt(q2+best) => bound
// passes after one round); growth loop kept for rare INF-seed outliers.
// Distance: |y|^2 - 2 q.y (fma chain) + |q|^2 at end (same arithmetic as
// the R2 brute force that scored absmax 0.0).

#define GF 64
#define GSHF 6
#define CCF (GF * GF * GF)      // 262144
#define HF 0.1f
#define INVHF 10.0f
#define ORIGF (-3.2f)
#define NCHF (CCF / 256)        // 1024
#define SSF 262160u             // ((CCF+1)*4 + 63 & ~63)/4 uints

#define G2 32
#define GSH2 5
#define CC2 (G2 * G2 * G2)      // 32768
#define H2 0.4f
#define INVH2 2.5f
#define ORIG2 (-6.4f)
#define NCH2 (CC2 / 256)        // 128
#define SS2 32784u              // ((CC2+1)*4 + 63 & ~63)/4 uints

#define INFB 3.4e38f

__device__ __forceinline__ int cellcoordF(float x) {
    int c = (int)floorf((x - ORIGF) * INVHF);
    return min(max(c, 0), GF - 1);
}
__device__ __forceinline__ int cellofF(float x, float y, float z) {
    return (cellcoordF(z) << (2 * GSHF)) + (cellcoordF(y) << GSHF) + cellcoordF(x);
}
__device__ __forceinline__ int cellcoord2(float x) {
    int c = (int)floorf((x - ORIG2) * INVH2);
    return min(max(c, 0), G2 - 1);
}
__device__ __forceinline__ int cellof2(float x, float y, float z) {
    return (cellcoord2(z) << (2 * GSH2)) + (cellcoord2(y) << GSH2) + cellcoord2(x);
}
// Conservative axis distance to coarse cell u's extent; edges open-ended.
__device__ __forceinline__ float axdist2(int u, float qc) {
    float lo = ORIG2 + u * H2;
    float dlo = (u == 0) ? 0.0f : lo - qc;
    float dhi = (u == G2 - 1) ? 0.0f : qc - (lo + H2);
    return fmaxf(0.0f, fmaxf(dlo, dhi));
}
__device__ __forceinline__ float scan_run(
    const float4* __restrict__ pts, unsigned int k, unsigned int ke,
    float cx, float cy, float cz, float lbest) {
    for (; k < ke; ++k) {
        float4 ya = pts[k];
        lbest = fminf(lbest, fmaf(cx, ya.x, fmaf(cy, ya.y, fmaf(cz, ya.z, ya.w))));
    }
    return lbest;
}

// ---- build: histogram both grids, both clouds ----
__global__ __launch_bounds__(256) void hist2_kernel(
    const float4* __restrict__ A, const float4* __restrict__ B,
    unsigned int* __restrict__ countsF, unsigned int* __restrict__ countsC,
    int n) {
    int i = blockIdx.x * 256 + threadIdx.x;
    const float4* in = blockIdx.y ? B : A;
    unsigned int* cF = countsF + (size_t)blockIdx.y * CCF;
    unsigned int* cC = countsC + (size_t)blockIdx.y * CC2;
    if (i < n) {
        float4 a = in[i];
        atomicAdd(&cF[cellofF(a.x, a.y, a.z)], 1u);
        atomicAdd(&cC[cellof2(a.x, a.y, a.z)], 1u);
    }
}

// ---- merged per-chunk scan: blocks [0, 2*NCHF) fine, rest coarse ----
__global__ __launch_bounds__(256) void scan_chunk_all_kernel(
    const unsigned int* __restrict__ countsF, unsigned int* __restrict__ exclF,
    unsigned int* __restrict__ bsF,
    const unsigned int* __restrict__ countsC, unsigned int* __restrict__ exclC,
    unsigned int* __restrict__ bsC) {
    __shared__ unsigned int lds[256];
    int bid = blockIdx.x;
    const unsigned int* cnt;
    unsigned int* excl;
    unsigned int* bsp;
    int g;
    if (bid < 2 * NCHF) {
        int b = bid >> 10, cb = bid & (NCHF - 1);
        g = cb * 256 + threadIdx.x;
        cnt = countsF + (size_t)b * CCF;
        excl = exclF + (size_t)b * SSF;
        bsp = bsF + bid;
    } else {
        int b2 = bid - 2 * NCHF;
        int b = b2 >> 7, cb = b2 & (NCH2 - 1);
        g = cb * 256 + threadIdx.x;
        cnt = countsC + (size_t)b * CC2;
        excl = exclC + (size_t)b * SS2;
        bsp = bsC + b2;
    }
    unsigned int v = cnt[g];
    lds[threadIdx.x] = v;
    __syncthreads();
    for (int off = 1; off < 256; off <<= 1) {
        unsigned int t = (threadIdx.x >= off) ? lds[threadIdx.x - off] : 0u;
        __syncthreads();
        lds[threadIdx.x] += t;
        __syncthreads();
    }
    excl[g] = lds[threadIdx.x] - v;
    if (threadIdx.x == 255) *bsp = lds[255];
}

// ---- merged block-sums scan: 4 blocks (2 fine clouds, 2 coarse clouds) ----
__global__ __launch_bounds__(256) void scan_sums_all_kernel(
    unsigned int* __restrict__ bsF, unsigned int* __restrict__ bsC) {
    int b = blockIdx.x;
    unsigned int* bs = (b < 2) ? bsF + b * NCHF : bsC + (b - 2) * NCH2;
    int len = (b < 2) ? NCHF : NCH2;
    __shared__ unsigned int lds[256];
    __shared__ unsigned int carrySh;
    if (threadIdx.x == 0) carrySh = 0;
    __syncthreads();
    for (int base = 0; base < len; base += 256) {
        int idx = base + threadIdx.x;
        unsigned int v = (idx < len) ? bs[idx] : 0u;
        lds[threadIdx.x] = v;
        __syncthreads();
        for (int off = 1; off < 256; off <<= 1) {
            unsigned int t = (threadIdx.x >= off) ? lds[threadIdx.x - off] : 0u;
            __syncthreads();
            lds[threadIdx.x] += t;
            __syncthreads();
        }
        unsigned int carry = carrySh;
        if (idx < len) bs[idx] = carry + lds[threadIdx.x] - v;  // exclusive
        __syncthreads();
        if (threadIdx.x == 255) carrySh = carry + lds[255];
        __syncthreads();
    }
}

// ---- merged add-offsets (also materializes scatter cursors + sentinel) ----
__global__ __launch_bounds__(256) void add_offsets_all_kernel(
    unsigned int* __restrict__ exclF, unsigned int* __restrict__ nextF,
    const unsigned int* __restrict__ bsF,
    unsigned int* __restrict__ exclC, unsigned int* __restrict__ nextC,
    const unsigned int* __restrict__ bsC, int n) {
    int bid = blockIdx.x;
    unsigned int* excl;
    unsigned int* next;
    unsigned int add;
    int g, cells;
    if (bid < 2 * NCHF) {
        int b = bid >> 10, cb = bid & (NCHF - 1);
        g = cb * 256 + threadIdx.x;
        excl = exclF + (size_t)b * SSF;
        next = nextF + (size_t)b * CCF;
        add = bsF[bid];
        cells = CCF;
    } else {
        int b2 = bid - 2 * NCHF;
        int b = b2 >> 7, cb = b2 & (NCH2 - 1);
        g = cb * 256 + threadIdx.x;
        excl = exclC + (size_t)b * SS2;
        next = nextC + (size_t)b * CC2;
        add = bsC[b2];
        cells = CC2;
    }
    unsigned int v = excl[g] + add;
    excl[g] = v;
    next[g] = v;
    if (g == 0) excl[cells] = (unsigned int)n;
}

// ---- merged scatter: one input read -> fine AND coarse sorted copies ----
__global__ __launch_bounds__(256) void scatter_all_kernel(
    const float4* __restrict__ A, const float4* __restrict__ B,
    unsigned int* __restrict__ nextF, unsigned int* __restrict__ nextC,
    float4* __restrict__ sortedF, float4* __restrict__ sortedC, int n) {
    int i = blockIdx.x * 256 + threadIdx.x;
    const float4* in = blockIdx.y ? B : A;
    unsigned int* nxF = nextF + (size_t)blockIdx.y * CCF;
    unsigned int* nxC = nextC + (size_t)blockIdx.y * CC2;
    float4* outF = sortedF + (size_t)blockIdx.y * n;
    float4* outC = sortedC + (size_t)blockIdx.y * n;
    if (i < n) {
        float4 a = in[i];
        float s = fmaf(a.x, a.x, fmaf(a.y, a.y, a.z * a.z));
        float4 pt = make_float4(a.x, a.y, a.z, s);
        unsigned int sF = atomicAdd(&nxF[cellofF(a.x, a.y, a.z)], 1u);
        outF[sF] = pt;
        unsigned int sC = atomicAdd(&nxC[cellof2(a.x, a.y, a.z)], 1u);
        outC[sC] = pt;
    }
}

// ---- pass 1: fine 27-cell neighborhood, both directions fused ----
__global__ __launch_bounds__(256) void nn_pass1_kernel(
    const float4* __restrict__ sortedF, const unsigned int* __restrict__ startF,
    int n, unsigned int* __restrict__ wlPT, unsigned int* __restrict__ wbPT,
    unsigned int* __restrict__ cnts, double* __restrict__ acc) {
    int dir = blockIdx.y;
    const float4* Q = sortedF + (size_t)dir * n;
    const float4* pts = sortedF + (size_t)(1 - dir) * n;
    const unsigned int* start = startF + (size_t)(1 - dir) * SSF;
    unsigned int* wl = wlPT + (size_t)dir * n;
    unsigned int* wb = wbPT + (size_t)dir * n;
    unsigned int* cnt = cnts + dir;

    int i = blockIdx.x * 256 + threadIdx.x;
    float v = 0.0f;
    if (i < n) {
        float4 q = Q[i];
        float cx = -2.0f * q.x, cy = -2.0f * q.y, cz = -2.0f * q.z;
        float q2 = q.w;
        int qx = cellcoordF(q.x), qy = cellcoordF(q.y), qz = cellcoordF(q.z);
        int x0 = max(qx - 1, 0), x1 = min(qx + 1, GF - 1);
        unsigned int ss[9], ee[9];
        int idx = 0;
#pragma unroll
        for (int dz = -1; dz <= 1; ++dz) {
            int uz = min(max(qz + dz, 0), GF - 1);
#pragma unroll
            for (int dy = -1; dy <= 1; ++dy) {
                int uy = min(max(qy + dy, 0), GF - 1);
                unsigned int base = ((unsigned)uz << (2 * GSHF)) + ((unsigned)uy << GSHF);
                ss[idx] = start[base + x0];
                ee[idx] = start[base + x1 + 1];
                ++idx;
            }
        }
        float best = INFB;
#pragma unroll
        for (int r = 0; r < 9; ++r) {
            unsigned int k = ss[r], e = ee[r];
            for (; k + 2 <= e; k += 2) {
                float4 ya = pts[k];
                float4 yb = pts[k + 1];
                float ea = fmaf(cx, ya.x, fmaf(cy, ya.y, fmaf(cz, ya.z, ya.w)));
                float eb = fmaf(cx, yb.x, fmaf(cy, yb.y, fmaf(cz, yb.z, yb.w)));
                best = fminf(fminf(best, ea), eb);
            }
            if (k < e) {
                float4 ya = pts[k];
                best = fminf(best, fmaf(cx, ya.x, fmaf(cy, ya.y, fmaf(cz, ya.z, ya.w))));
            }
        }
        float ba = q2 + best;
        // exact finality bound: min distance from q to any unscanned fine
        // cell. fx may be negative for clamped (out-of-box) queries; the
        // formulas remain the exact distances to the unscanned region.
        float fx = q.x - (ORIGF + (float)qx * HF);
        float fy = q.y - (ORIGF + (float)qy * HF);
        float fz = q.z - (ORIGF + (float)qz * HF);
        float bx = fminf((qx >= 2) ? (fx + HF) : INFB,
                         (qx <= GF - 3) ? (2.0f * HF - fx) : INFB);
        float by = fminf((qy >= 2) ? (fy + HF) : INFB,
                         (qy <= GF - 3) ? (2.0f * HF - fy) : INFB);
        float bz = fminf((qz >= 2) ? (fz + HF) : INFB,
                         (qz <= GF - 3) ? (2.0f * HF - fz) : INFB);
        float bound = fminf(bx, fminf(by, bz)) * 0.99999f;  // ulp safety
        if (ba <= bound * bound) {
            v = ba;
        } else {
            unsigned int w = atomicAdd(cnt, 1u);
            wl[w] = (unsigned int)i;
            wb[w] = __float_as_uint(best);  // relative best handoff
        }
    }
    for (int off = 32; off > 0; off >>= 1) v += __shfl_down(v, off);
    __shared__ float partial[4];
    int lane = threadIdx.x & 63, wid = threadIdx.x >> 6;
    if (lane == 0) partial[wid] = v;
    __syncthreads();
    if (threadIdx.x == 0)
        atomicAdd(acc, (double)((partial[0] + partial[1]) + (partial[2] + partial[3])));
}

// ---- pass 2: wave/query, one-shot coarse box scan (seeded radius) ----
__global__ __launch_bounds__(256) void nn_pass2_kernel(
    const float4* __restrict__ sortedF, const float4* __restrict__ sortedC,
    const unsigned int* __restrict__ startC,
    int n, const unsigned int* __restrict__ wlPT, const unsigned int* __restrict__ wbPT,
    const unsigned int* __restrict__ cnts, double* __restrict__ acc) {
    int dir = blockIdx.y;
    const float4* Q = sortedF + (size_t)dir * n;
    const float4* pts = sortedC + (size_t)(1 - dir) * n;
    const unsigned int* start = startC + (size_t)(1 - dir) * SS2;
    const unsigned int* wl = wlPT + (size_t)dir * n;
    const unsigned int* wb = wbPT + (size_t)dir * n;
    unsigned int m = cnts[dir];

    int lane = threadIdx.x & 63;
    int gwave = (blockIdx.x * 256 + threadIdx.x) >> 6;
    int nwave = gridDim.x * 4;
    float wsum = 0.0f;
    for (unsigned int e = gwave; e < m; e += (unsigned int)nwave) {
        unsigned int qi = wl[e];
        float4 q = Q[qi];
        float cx = -2.0f * q.x, cy = -2.0f * q.y, cz = -2.0f * q.z;
        float q2 = q.w;
        int qx = cellcoord2(q.x), qy = cellcoord2(q.y), qz = cellcoord2(q.z);
        float fx = q.x - (ORIG2 + (float)qx * H2);
        float fy = q.y - (ORIG2 + (float)qy * H2);
        float fz = q.z - (ORIG2 + (float)qz * H2);
        float best = __uint_as_float(wb[e]);  // seeded from pass1
        // one-shot radius: Rb*H2 >= sqrt(q2+best) makes the bound pass
        // after a single round (typical straggler: Rb=1).
        float D = sqrtf(fminf(q2 + best, 16.0f));
        int Rb = (int)ceilf(D * INVH2);
        Rb = min(max(Rb, 1), 4);   // cap start; growth handles INF seeds
        int Rp = -1;               // nothing coarse-covered yet
        for (;;) {
            int z0 = max(qz - Rb, 0), z1 = min(qz + Rb, G2 - 1);
            int y0 = max(qy - Rb, 0), y1 = min(qy + Rb, G2 - 1);
            int x0 = max(qx - Rb, 0), x1 = min(qx + Rb, G2 - 1);
            int nyr = y1 - y0 + 1;
            int nrows = (z1 - z0 + 1) * nyr;
            float lbest = best;
            for (int r = lane; r < nrows; r += 64) {
                int uz = z0 + r / nyr;
                int uy = y0 + r % nyr;
                int az = uz > qz ? uz - qz : qz - uz;
                int ay = uy > qy ? uy - qy : qy - uy;
                float dz = axdist2(uz, q.z), dy = axdist2(uy, q.y);
                float rowd2 = fmaf(dz, dz, dy * dy);
                if (rowd2 >= q2 + lbest) continue;
                unsigned int base = ((unsigned)uz << (2 * GSH2)) + ((unsigned)uy << GSH2);
                if (az <= Rp && ay <= Rp) {
                    // inner row: only x beyond the previously covered box is new
                    int xa1 = qx - Rp - 1;
                    int xb0 = qx + Rp + 1;
                    if (xa1 >= x0)
                        lbest = scan_run(pts, start[base + x0], start[base + xa1 + 1],
                                         cx, cy, cz, lbest);
                    if (xb0 <= x1)
                        lbest = scan_run(pts, start[base + xb0], start[base + x1 + 1],
                                         cx, cy, cz, lbest);
                } else {
                    lbest = scan_run(pts, start[base + x0], start[base + x1 + 1],
                                     cx, cy, cz, lbest);
                }
            }
            for (int off = 32; off > 0; off >>= 1)
                lbest = fminf(lbest, __shfl_xor(lbest, off));
            best = lbest;
            // exact termination: min distance from q to any cell outside +-Rb
            float bx = fminf((qx - Rb >= 1) ? fmaf((float)Rb, H2, fx) : INFB,
                             (qx + Rb + 1 <= G2 - 1) ? ((float)(Rb + 1) * H2 - fx) : INFB);
            float by = fminf((qy - Rb >= 1) ? fmaf((float)Rb, H2, fy) : INFB,
                             (qy + Rb + 1 <= G2 - 1) ? ((float)(Rb + 1) * H2 - fy) : INFB);
            float bz = fminf((qz - Rb >= 1) ? fmaf((float)Rb, H2, fz) : INFB,
                             (qz + Rb + 1 <= G2 - 1) ? ((float)(Rb + 1) * H2 - fz) : INFB);
            float bound = fminf(bx, fminf(by, bz)) * 0.99999f;
            if (q2 + best <= bound * bound || Rb >= G2) break;
            Rp = Rb;
            Rb = min(Rb + 1, G2);
        }
        wsum += q2 + best;
    }
    if (lane == 0 && wsum != 0.0f) atomicAdd(acc, (double)wsum);
}

__global__ void finalize_kernel(const double* __restrict__ acc,
                                float* __restrict__ out, int n) {
    out[0] = (float)(acc[0] / (double)n);
}

// ---- fallback: R2 brute-force (proven, absmax 0.0) ----
#define SPLIT 16
#define PTS 4
__global__ __launch_bounds__(256) void pack_kernel(
    const float4* __restrict__ in, float4* __restrict__ out, int n) {
    int i = blockIdx.x * 256 + threadIdx.x;
    if (i < n) {
        float4 a = in[i];
        float s = fmaf(a.x, a.x, fmaf(a.y, a.y, a.z * a.z));
        out[i] = make_float4(a.x, a.y, a.z, s);
    }
}
__device__ __forceinline__ unsigned int enc_f32(float f) {
    unsigned int u = __float_as_uint(f);
    return (u & 0x80000000u) ? ~u : (u | 0x80000000u);
}
__device__ __forceinline__ float dec_f32(unsigned int u) {
    u = (u & 0x80000000u) ? (u ^ 0x80000000u) : ~u;
    return __uint_as_float(u);
}
__global__ __launch_bounds__(256) void chamfer_dir_kernel(
    const float4* __restrict__ X, const float4* __restrict__ Y,
    int m, unsigned int* __restrict__ mins) {
    int base = blockIdx.x * (256 * PTS) + threadIdx.x;
    float x2x[PTS], x2y[PTS], x2z[PTS], xw[PTS], mn[PTS];
#pragma unroll
    for (int p = 0; p < PTS; ++p) {
        float4 x = X[base + p * 256];
        x2x[p] = -2.0f * x.x; x2y[p] = -2.0f * x.y; x2z[p] = -2.0f * x.z;
        xw[p] = x.w; mn[p] = INFB;
    }
    int seglen = m / SPLIT, j0 = blockIdx.y * seglen, j1 = j0 + seglen;
    for (int j = j0; j < j1; j += 8) {
#pragma unroll
        for (int u = 0; u < 8; u += 2) {
            float4 ya = Y[j + u];
            float4 yb = Y[j + u + 1];
#pragma unroll
            for (int p = 0; p < PTS; ++p) {
                float ea = fmaf(x2x[p], ya.x, fmaf(x2y[p], ya.y, fmaf(x2z[p], ya.z, ya.w)));
                float eb = fmaf(x2x[p], yb.x, fmaf(x2y[p], yb.y, fmaf(x2z[p], yb.z, yb.w)));
                mn[p] = fminf(fminf(mn[p], ea), eb);
            }
        }
    }
#pragma unroll
    for (int p = 0; p < PTS; ++p)
        atomicMin(&mins[base + p * 256], enc_f32(xw[p] + mn[p]));
}
__global__ __launch_bounds__(256) void reduce_kernel(
    const unsigned int* __restrict__ mins, int total, double* __restrict__ acc) {
    float s = 0.0f;
    for (int i = blockIdx.x * 256 + threadIdx.x; i < total; i += gridDim.x * 256)
        s += dec_f32(mins[i]);
    for (int off = 32; off > 0; off >>= 1) s += __shfl_down(s, off);
    __shared__ float partial[4];
    int lane = threadIdx.x & 63, wid = threadIdx.x >> 6;
    if (lane == 0) partial[wid] = s;
    __syncthreads();
    if (threadIdx.x == 0)
        atomicAdd(acc, (double)((partial[0] + partial[1]) + (partial[2] + partial[3])));
}

extern "C" void kernel_launch(void* const* d_in, const int* in_sizes, int n_in,
                              void* d_out, int out_size, void* d_ws, size_t ws_size,
                              hipStream_t stream) {
    const float4* pred = (const float4*)d_in[0];
    const float4* targ = (const float4*)d_in[1];
    float* out = (float*)d_out;
    int n = in_sizes[0] / 4;  // 131072 points
    int nblk = (n + 255) / 256;

    char* ws = (char*)d_ws;
    double* acc = (double*)ws;                     // [0,8)
    unsigned int* cnts = (unsigned int*)(ws + 8);  // [8,16): cntP, cntT

    size_t startFB = (size_t)SSF * 4;
    size_t startCB = (size_t)SS2 * 4;
    size_t needGrid = 64 + 2 * startFB + 2 * startCB + 2ull * CCF * 4
                    + 2ull * CC2 * 4 + 4ull * n * 16 + 4ull * n * 4
                    + 2ull * NCHF * 4 + 2ull * NCH2 * 4;

    if (ws_size >= needGrid && n == 131072) {
        char* p = ws + 64;
        unsigned int* startF = (unsigned int*)p;   p += 2 * startFB;
        unsigned int* startC = (unsigned int*)p;   p += 2 * startCB;
        unsigned int* nextF = (unsigned int*)p;    p += 2ull * CCF * 4;
        unsigned int* nextC = (unsigned int*)p;    p += 2ull * CC2 * 4;
        float4* sortedF = (float4*)p;              p += 2ull * n * 16;
        float4* sortedC = (float4*)p;              p += 2ull * n * 16;
        unsigned int* wlPT = (unsigned int*)p;     p += 2ull * n * 4;
        unsigned int* wbPT = (unsigned int*)p;     p += 2ull * n * 4;
        unsigned int* bsF = (unsigned int*)p;      p += 2ull * NCHF * 4;
        unsigned int* bsC = (unsigned int*)p;

        hipMemsetAsync(ws, 0, 64, stream);  // acc + cnts
        // fine counts + coarse counts are adjacent: one memset
        hipMemsetAsync(nextF, 0, 2ull * CCF * 4 + 2ull * CC2 * 4, stream);
        hist2_kernel<<<dim3(nblk, 2), 256, 0, stream>>>(pred, targ, nextF, nextC, n);
        scan_chunk_all_kernel<<<2 * NCHF + 2 * NCH2, 256, 0, stream>>>(
            nextF, startF, bsF, nextC, startC, bsC);
        scan_sums_all_kernel<<<4, 256, 0, stream>>>(bsF, bsC);
        add_offsets_all_kernel<<<2 * NCHF + 2 * NCH2, 256, 0, stream>>>(
            startF, nextF, bsF, startC, nextC, bsC, n);
        scatter_all_kernel<<<dim3(nblk, 2), 256, 0, stream>>>(
            pred, targ, nextF, nextC, sortedF, sortedC, n);

        nn_pass1_kernel<<<dim3(nblk, 2), 256, 0, stream>>>(
            sortedF, startF, n, wlPT, wbPT, cnts, acc);
        nn_pass2_kernel<<<dim3(1024, 2), 256, 0, stream>>>(
            sortedF, sortedC, startC, n, wlPT, wbPT, cnts, acc);
    } else {
        hipMemsetAsync(acc, 0, sizeof(double), stream);
        size_t needBF = 64 + 2ull * n * sizeof(float4) + 2ull * n * sizeof(unsigned int);
        if (ws_size >= needBF && (n % (256 * PTS)) == 0 && (n % SPLIT) == 0) {
            float4* P = (float4*)(ws + 64);
            float4* T = P + n;
            unsigned int* minPT = (unsigned int*)(T + n);
            pack_kernel<<<nblk, 256, 0, stream>>>(pred, P, n);
            pack_kernel<<<nblk, 256, 0, stream>>>(targ, T, n);
            hipMemsetAsync(minPT, 0xFF, 2ull * n * sizeof(unsigned int), stream);
            dim3 grid(n / (256 * PTS), SPLIT);
            chamfer_dir_kernel<<<grid, 256, 0, stream>>>(P, T, n, minPT);
            chamfer_dir_kernel<<<grid, 256, 0, stream>>>(T, P, n, minPT + n);
            reduce_kernel<<<256, 256, 0, stream>>>(minPT, 2 * n, acc);
        }
    }
    finalize_kernel<<<1, 1, 0, stream>>>(acc, out, n);
}

// Round 11
// 286.466 us; speedup vs baseline: 2.5708x; 2.5708x over previous
//
#include <hip/hip_runtime.h>

// Chamfer distance via exact two-level uniform-grid NN search.
// FINE grid 64^3, h=0.1, box [-3.2,3.2] (clamped; exact: edge cells are
// open-ended in the finality bound, clamped points are extra candidates).
// COARSE grid 32^3, h2=0.4, box [-6.4,6.4] (all points interior).
// Pass1 (thread/query, dirs fused): fine 27-cell scan; final iff
// best <= bound^2 (exact distance to unscanned region). Else worklist.
// Pass2 (wave/query, static interleave): incremental ring-growing coarse
// scan with Rp inner-skip. HYBRID start radius: INF seed -> Rb0=1 (builds
// pruning bound incrementally, avoids unpruned big-box scans — the R10
// regression); finite seed -> Rb0 from seed (pruning active immediately).
// Distance: |y|^2 - 2 q.y (fma chain) + |q|^2 at end (same arithmetic as
// the R2 brute force that scored absmax 0.0).

#define GF 64
#define GSHF 6
#define CCF (GF * GF * GF)      // 262144
#define HF 0.1f
#define INVHF 10.0f
#define ORIGF (-3.2f)
#define NCHF (CCF / 256)        // 1024
#define SSF 262160u             // ((CCF+1)*4 + 63 & ~63)/4 uints

#define G2 32
#define GSH2 5
#define CC2 (G2 * G2 * G2)      // 32768
#define H2 0.4f
#define INVH2 2.5f
#define ORIG2 (-6.4f)
#define NCH2 (CC2 / 256)        // 128
#define SS2 32784u              // ((CC2+1)*4 + 63 & ~63)/4 uints

#define INFB 3.4e38f

__device__ __forceinline__ int cellcoordF(float x) {
    int c = (int)floorf((x - ORIGF) * INVHF);
    return min(max(c, 0), GF - 1);
}
__device__ __forceinline__ int cellofF(float x, float y, float z) {
    return (cellcoordF(z) << (2 * GSHF)) + (cellcoordF(y) << GSHF) + cellcoordF(x);
}
__device__ __forceinline__ int cellcoord2(float x) {
    int c = (int)floorf((x - ORIG2) * INVH2);
    return min(max(c, 0), G2 - 1);
}
__device__ __forceinline__ int cellof2(float x, float y, float z) {
    return (cellcoord2(z) << (2 * GSH2)) + (cellcoord2(y) << GSH2) + cellcoord2(x);
}
// Conservative axis distance to coarse cell u's extent; edges open-ended.
__device__ __forceinline__ float axdist2(int u, float qc) {
    float lo = ORIG2 + u * H2;
    float dlo = (u == 0) ? 0.0f : lo - qc;
    float dhi = (u == G2 - 1) ? 0.0f : qc - (lo + H2);
    return fmaxf(0.0f, fmaxf(dlo, dhi));
}
__device__ __forceinline__ float scan_run(
    const float4* __restrict__ pts, unsigned int k, unsigned int ke,
    float cx, float cy, float cz, float lbest) {
    for (; k < ke; ++k) {
        float4 ya = pts[k];
        lbest = fminf(lbest, fmaf(cx, ya.x, fmaf(cy, ya.y, fmaf(cz, ya.z, ya.w))));
    }
    return lbest;
}

// ---- build: histogram both grids, both clouds ----
__global__ __launch_bounds__(256) void hist2_kernel(
    const float4* __restrict__ A, const float4* __restrict__ B,
    unsigned int* __restrict__ countsF, unsigned int* __restrict__ countsC,
    int n) {
    int i = blockIdx.x * 256 + threadIdx.x;
    const float4* in = blockIdx.y ? B : A;
    unsigned int* cF = countsF + (size_t)blockIdx.y * CCF;
    unsigned int* cC = countsC + (size_t)blockIdx.y * CC2;
    if (i < n) {
        float4 a = in[i];
        atomicAdd(&cF[cellofF(a.x, a.y, a.z)], 1u);
        atomicAdd(&cC[cellof2(a.x, a.y, a.z)], 1u);
    }
}

// ---- merged per-chunk scan: blocks [0, 2*NCHF) fine, rest coarse ----
__global__ __launch_bounds__(256) void scan_chunk_all_kernel(
    const unsigned int* __restrict__ countsF, unsigned int* __restrict__ exclF,
    unsigned int* __restrict__ bsF,
    const unsigned int* __restrict__ countsC, unsigned int* __restrict__ exclC,
    unsigned int* __restrict__ bsC) {
    __shared__ unsigned int lds[256];
    int bid = blockIdx.x;
    const unsigned int* cnt;
    unsigned int* excl;
    unsigned int* bsp;
    int g;
    if (bid < 2 * NCHF) {
        int b = bid >> 10, cb = bid & (NCHF - 1);
        g = cb * 256 + threadIdx.x;
        cnt = countsF + (size_t)b * CCF;
        excl = exclF + (size_t)b * SSF;
        bsp = bsF + bid;
    } else {
        int b2 = bid - 2 * NCHF;
        int b = b2 >> 7, cb = b2 & (NCH2 - 1);
        g = cb * 256 + threadIdx.x;
        cnt = countsC + (size_t)b * CC2;
        excl = exclC + (size_t)b * SS2;
        bsp = bsC + b2;
    }
    unsigned int v = cnt[g];
    lds[threadIdx.x] = v;
    __syncthreads();
    for (int off = 1; off < 256; off <<= 1) {
        unsigned int t = (threadIdx.x >= off) ? lds[threadIdx.x - off] : 0u;
        __syncthreads();
        lds[threadIdx.x] += t;
        __syncthreads();
    }
    excl[g] = lds[threadIdx.x] - v;
    if (threadIdx.x == 255) *bsp = lds[255];
}

// ---- merged block-sums scan: 4 blocks (2 fine clouds, 2 coarse clouds) ----
__global__ __launch_bounds__(256) void scan_sums_all_kernel(
    unsigned int* __restrict__ bsF, unsigned int* __restrict__ bsC) {
    int b = blockIdx.x;
    unsigned int* bs = (b < 2) ? bsF + b * NCHF : bsC + (b - 2) * NCH2;
    int len = (b < 2) ? NCHF : NCH2;
    __shared__ unsigned int lds[256];
    __shared__ unsigned int carrySh;
    if (threadIdx.x == 0) carrySh = 0;
    __syncthreads();
    for (int base = 0; base < len; base += 256) {
        int idx = base + threadIdx.x;
        unsigned int v = (idx < len) ? bs[idx] : 0u;
        lds[threadIdx.x] = v;
        __syncthreads();
        for (int off = 1; off < 256; off <<= 1) {
            unsigned int t = (threadIdx.x >= off) ? lds[threadIdx.x - off] : 0u;
            __syncthreads();
            lds[threadIdx.x] += t;
            __syncthreads();
        }
        unsigned int carry = carrySh;
        if (idx < len) bs[idx] = carry + lds[threadIdx.x] - v;  // exclusive
        __syncthreads();
        if (threadIdx.x == 255) carrySh = carry + lds[255];
        __syncthreads();
    }
}

// ---- merged add-offsets (also materializes scatter cursors + sentinel) ----
__global__ __launch_bounds__(256) void add_offsets_all_kernel(
    unsigned int* __restrict__ exclF, unsigned int* __restrict__ nextF,
    const unsigned int* __restrict__ bsF,
    unsigned int* __restrict__ exclC, unsigned int* __restrict__ nextC,
    const unsigned int* __restrict__ bsC, int n) {
    int bid = blockIdx.x;
    unsigned int* excl;
    unsigned int* next;
    unsigned int add;
    int g, cells;
    if (bid < 2 * NCHF) {
        int b = bid >> 10, cb = bid & (NCHF - 1);
        g = cb * 256 + threadIdx.x;
        excl = exclF + (size_t)b * SSF;
        next = nextF + (size_t)b * CCF;
        add = bsF[bid];
        cells = CCF;
    } else {
        int b2 = bid - 2 * NCHF;
        int b = b2 >> 7, cb = b2 & (NCH2 - 1);
        g = cb * 256 + threadIdx.x;
        excl = exclC + (size_t)b * SS2;
        next = nextC + (size_t)b * CC2;
        add = bsC[b2];
        cells = CC2;
    }
    unsigned int v = excl[g] + add;
    excl[g] = v;
    next[g] = v;
    if (g == 0) excl[cells] = (unsigned int)n;
}

// ---- merged scatter: one input read -> fine AND coarse sorted copies ----
__global__ __launch_bounds__(256) void scatter_all_kernel(
    const float4* __restrict__ A, const float4* __restrict__ B,
    unsigned int* __restrict__ nextF, unsigned int* __restrict__ nextC,
    float4* __restrict__ sortedF, float4* __restrict__ sortedC, int n) {
    int i = blockIdx.x * 256 + threadIdx.x;
    const float4* in = blockIdx.y ? B : A;
    unsigned int* nxF = nextF + (size_t)blockIdx.y * CCF;
    unsigned int* nxC = nextC + (size_t)blockIdx.y * CC2;
    float4* outF = sortedF + (size_t)blockIdx.y * n;
    float4* outC = sortedC + (size_t)blockIdx.y * n;
    if (i < n) {
        float4 a = in[i];
        float s = fmaf(a.x, a.x, fmaf(a.y, a.y, a.z * a.z));
        float4 pt = make_float4(a.x, a.y, a.z, s);
        unsigned int sF = atomicAdd(&nxF[cellofF(a.x, a.y, a.z)], 1u);
        outF[sF] = pt;
        unsigned int sC = atomicAdd(&nxC[cellof2(a.x, a.y, a.z)], 1u);
        outC[sC] = pt;
    }
}

// ---- pass 1: fine 27-cell neighborhood, both directions fused ----
__global__ __launch_bounds__(256) void nn_pass1_kernel(
    const float4* __restrict__ sortedF, const unsigned int* __restrict__ startF,
    int n, unsigned int* __restrict__ wlPT, unsigned int* __restrict__ wbPT,
    unsigned int* __restrict__ cnts, double* __restrict__ acc) {
    int dir = blockIdx.y;
    const float4* Q = sortedF + (size_t)dir * n;
    const float4* pts = sortedF + (size_t)(1 - dir) * n;
    const unsigned int* start = startF + (size_t)(1 - dir) * SSF;
    unsigned int* wl = wlPT + (size_t)dir * n;
    unsigned int* wb = wbPT + (size_t)dir * n;
    unsigned int* cnt = cnts + dir;

    int i = blockIdx.x * 256 + threadIdx.x;
    float v = 0.0f;
    if (i < n) {
        float4 q = Q[i];
        float cx = -2.0f * q.x, cy = -2.0f * q.y, cz = -2.0f * q.z;
        float q2 = q.w;
        int qx = cellcoordF(q.x), qy = cellcoordF(q.y), qz = cellcoordF(q.z);
        int x0 = max(qx - 1, 0), x1 = min(qx + 1, GF - 1);
        unsigned int ss[9], ee[9];
        int idx = 0;
#pragma unroll
        for (int dz = -1; dz <= 1; ++dz) {
            int uz = min(max(qz + dz, 0), GF - 1);
#pragma unroll
            for (int dy = -1; dy <= 1; ++dy) {
                int uy = min(max(qy + dy, 0), GF - 1);
                unsigned int base = ((unsigned)uz << (2 * GSHF)) + ((unsigned)uy << GSHF);
                ss[idx] = start[base + x0];
                ee[idx] = start[base + x1 + 1];
                ++idx;
            }
        }
        float best = INFB;
#pragma unroll
        for (int r = 0; r < 9; ++r) {
            unsigned int k = ss[r], e = ee[r];
            for (; k + 2 <= e; k += 2) {
                float4 ya = pts[k];
                float4 yb = pts[k + 1];
                float ea = fmaf(cx, ya.x, fmaf(cy, ya.y, fmaf(cz, ya.z, ya.w)));
                float eb = fmaf(cx, yb.x, fmaf(cy, yb.y, fmaf(cz, yb.z, yb.w)));
                best = fminf(fminf(best, ea), eb);
            }
            if (k < e) {
                float4 ya = pts[k];
                best = fminf(best, fmaf(cx, ya.x, fmaf(cy, ya.y, fmaf(cz, ya.z, ya.w))));
            }
        }
        float ba = q2 + best;
        // exact finality bound: min distance from q to any unscanned fine
        // cell. fx may be negative for clamped (out-of-box) queries; the
        // formulas remain the exact distances to the unscanned region.
        float fx = q.x - (ORIGF + (float)qx * HF);
        float fy = q.y - (ORIGF + (float)qy * HF);
        float fz = q.z - (ORIGF + (float)qz * HF);
        float bx = fminf((qx >= 2) ? (fx + HF) : INFB,
                         (qx <= GF - 3) ? (2.0f * HF - fx) : INFB);
        float by = fminf((qy >= 2) ? (fy + HF) : INFB,
                         (qy <= GF - 3) ? (2.0f * HF - fy) : INFB);
        float bz = fminf((qz >= 2) ? (fz + HF) : INFB,
                         (qz <= GF - 3) ? (2.0f * HF - fz) : INFB);
        float bound = fminf(bx, fminf(by, bz)) * 0.99999f;  // ulp safety
        if (ba <= bound * bound) {
            v = ba;
        } else {
            unsigned int w = atomicAdd(cnt, 1u);
            wl[w] = (unsigned int)i;
            wb[w] = __float_as_uint(best);  // relative best handoff
        }
    }
    for (int off = 32; off > 0; off >>= 1) v += __shfl_down(v, off);
    __shared__ float partial[4];
    int lane = threadIdx.x & 63, wid = threadIdx.x >> 6;
    if (lane == 0) partial[wid] = v;
    __syncthreads();
    if (threadIdx.x == 0)
        atomicAdd(acc, (double)((partial[0] + partial[1]) + (partial[2] + partial[3])));
}

// ---- pass 2: wave/query, ring-growing coarse scan, hybrid seeded start ----
__global__ __launch_bounds__(256) void nn_pass2_kernel(
    const float4* __restrict__ sortedF, const float4* __restrict__ sortedC,
    const unsigned int* __restrict__ startC,
    int n, const unsigned int* __restrict__ wlPT, const unsigned int* __restrict__ wbPT,
    const unsigned int* __restrict__ cnts, double* __restrict__ acc) {
    int dir = blockIdx.y;
    const float4* Q = sortedF + (size_t)dir * n;
    const float4* pts = sortedC + (size_t)(1 - dir) * n;
    const unsigned int* start = startC + (size_t)(1 - dir) * SS2;
    const unsigned int* wl = wlPT + (size_t)dir * n;
    const unsigned int* wb = wbPT + (size_t)dir * n;
    unsigned int m = cnts[dir];

    int lane = threadIdx.x & 63;
    int gwave = (blockIdx.x * 256 + threadIdx.x) >> 6;
    int nwave = gridDim.x * 4;
    float wsum = 0.0f;
    for (unsigned int e = gwave; e < m; e += (unsigned int)nwave) {
        unsigned int qi = wl[e];
        float4 q = Q[qi];
        float cx = -2.0f * q.x, cy = -2.0f * q.y, cz = -2.0f * q.z;
        float q2 = q.w;
        int qx = cellcoord2(q.x), qy = cellcoord2(q.y), qz = cellcoord2(q.z);
        float fx = q.x - (ORIG2 + (float)qx * H2);
        float fy = q.y - (ORIG2 + (float)qy * H2);
        float fz = q.z - (ORIG2 + (float)qz * H2);
        float best = __uint_as_float(wb[e]);  // seeded from pass1
        // HYBRID start: INF seed -> Rb=1 (pruning bound built incrementally);
        // finite seed -> one-shot radius, pruning active from round 1.
        int Rb = 1;
        if (best < INFB) {
            float D = sqrtf(fmaxf(q2 + best, 0.0f));
            Rb = min(max((int)ceilf(D * INVH2), 1), 3);
        }
        int Rp = -1;  // nothing coarse-covered yet
        for (;;) {
            int z0 = max(qz - Rb, 0), z1 = min(qz + Rb, G2 - 1);
            int y0 = max(qy - Rb, 0), y1 = min(qy + Rb, G2 - 1);
            int x0 = max(qx - Rb, 0), x1 = min(qx + Rb, G2 - 1);
            int nyr = y1 - y0 + 1;
            int nrows = (z1 - z0 + 1) * nyr;
            float lbest = best;
            for (int r = lane; r < nrows; r += 64) {
                int uz = z0 + r / nyr;
                int uy = y0 + r % nyr;
                int az = uz > qz ? uz - qz : qz - uz;
                int ay = uy > qy ? uy - qy : qy - uy;
                float dz = axdist2(uz, q.z), dy = axdist2(uy, q.y);
                float rowd2 = fmaf(dz, dz, dy * dy);
                if (rowd2 >= q2 + lbest) continue;
                unsigned int base = ((unsigned)uz << (2 * GSH2)) + ((unsigned)uy << GSH2);
                if (az <= Rp && ay <= Rp) {
                    // inner row: only x beyond the previously covered box is new
                    int xa1 = qx - Rp - 1;
                    int xb0 = qx + Rp + 1;
                    if (xa1 >= x0)
                        lbest = scan_run(pts, start[base + x0], start[base + xa1 + 1],
                                         cx, cy, cz, lbest);
                    if (xb0 <= x1)
                        lbest = scan_run(pts, start[base + xb0], start[base + x1 + 1],
                                         cx, cy, cz, lbest);
                } else {
                    lbest = scan_run(pts, start[base + x0], start[base + x1 + 1],
                                     cx, cy, cz, lbest);
                }
            }
            for (int off = 32; off > 0; off >>= 1)
                lbest = fminf(lbest, __shfl_xor(lbest, off));
            best = lbest;
            // exact termination: min distance from q to any cell outside +-Rb
            float bx = fminf((qx - Rb >= 1) ? fmaf((float)Rb, H2, fx) : INFB,
                             (qx + Rb + 1 <= G2 - 1) ? ((float)(Rb + 1) * H2 - fx) : INFB);
            float by = fminf((qy - Rb >= 1) ? fmaf((float)Rb, H2, fy) : INFB,
                             (qy + Rb + 1 <= G2 - 1) ? ((float)(Rb + 1) * H2 - fy) : INFB);
            float bz = fminf((qz - Rb >= 1) ? fmaf((float)Rb, H2, fz) : INFB,
                             (qz + Rb + 1 <= G2 - 1) ? ((float)(Rb + 1) * H2 - fz) : INFB);
            float bound = fminf(bx, fminf(by, bz)) * 0.99999f;
            if (q2 + best <= bound * bound || Rb >= G2) break;
            Rp = Rb;
            Rb = min(Rb + 1, G2);
        }
        wsum += q2 + best;
    }
    if (lane == 0 && wsum != 0.0f) atomicAdd(acc, (double)wsum);
}

__global__ void finalize_kernel(const double* __restrict__ acc,
                                float* __restrict__ out, int n) {
    out[0] = (float)(acc[0] / (double)n);
}

// ---- fallback: R2 brute-force (proven, absmax 0.0) ----
#define SPLIT 16
#define PTS 4
__global__ __launch_bounds__(256) void pack_kernel(
    const float4* __restrict__ in, float4* __restrict__ out, int n) {
    int i = blockIdx.x * 256 + threadIdx.x;
    if (i < n) {
        float4 a = in[i];
        float s = fmaf(a.x, a.x, fmaf(a.y, a.y, a.z * a.z));
        out[i] = make_float4(a.x, a.y, a.z, s);
    }
}
__device__ __forceinline__ unsigned int enc_f32(float f) {
    unsigned int u = __float_as_uint(f);
    return (u & 0x80000000u) ? ~u : (u | 0x80000000u);
}
__device__ __forceinline__ float dec_f32(unsigned int u) {
    u = (u & 0x80000000u) ? (u ^ 0x80000000u) : ~u;
    return __uint_as_float(u);
}
__global__ __launch_bounds__(256) void chamfer_dir_kernel(
    const float4* __restrict__ X, const float4* __restrict__ Y,
    int m, unsigned int* __restrict__ mins) {
    int base = blockIdx.x * (256 * PTS) + threadIdx.x;
    float x2x[PTS], x2y[PTS], x2z[PTS], xw[PTS], mn[PTS];
#pragma unroll
    for (int p = 0; p < PTS; ++p) {
        float4 x = X[base + p * 256];
        x2x[p] = -2.0f * x.x; x2y[p] = -2.0f * x.y; x2z[p] = -2.0f * x.z;
        xw[p] = x.w; mn[p] = INFB;
    }
    int seglen = m / SPLIT, j0 = blockIdx.y * seglen, j1 = j0 + seglen;
    for (int j = j0; j < j1; j += 8) {
#pragma unroll
        for (int u = 0; u < 8; u += 2) {
            float4 ya = Y[j + u];
            float4 yb = Y[j + u + 1];
#pragma unroll
            for (int p = 0; p < PTS; ++p) {
                float ea = fmaf(x2x[p], ya.x, fmaf(x2y[p], ya.y, fmaf(x2z[p], ya.z, ya.w)));
                float eb = fmaf(x2x[p], yb.x, fmaf(x2y[p], yb.y, fmaf(x2z[p], yb.z, yb.w)));
                mn[p] = fminf(fminf(mn[p], ea), eb);
            }
        }
    }
#pragma unroll
    for (int p = 0; p < PTS; ++p)
        atomicMin(&mins[base + p * 256], enc_f32(xw[p] + mn[p]));
}
__global__ __launch_bounds__(256) void reduce_kernel(
    const unsigned int* __restrict__ mins, int total, double* __restrict__ acc) {
    float s = 0.0f;
    for (int i = blockIdx.x * 256 + threadIdx.x; i < total; i += gridDim.x * 256)
        s += dec_f32(mins[i]);
    for (int off = 32; off > 0; off >>= 1) s += __shfl_down(s, off);
    __shared__ float partial[4];
    int lane = threadIdx.x & 63, wid = threadIdx.x >> 6;
    if (lane == 0) partial[wid] = s;
    __syncthreads();
    if (threadIdx.x == 0)
        atomicAdd(acc, (double)((partial[0] + partial[1]) + (partial[2] + partial[3])));
}

extern "C" void kernel_launch(void* const* d_in, const int* in_sizes, int n_in,
                              void* d_out, int out_size, void* d_ws, size_t ws_size,
                              hipStream_t stream) {
    const float4* pred = (const float4*)d_in[0];
    const float4* targ = (const float4*)d_in[1];
    float* out = (float*)d_out;
    int n = in_sizes[0] / 4;  // 131072 points
    int nblk = (n + 255) / 256;

    char* ws = (char*)d_ws;
    double* acc = (double*)ws;                     // [0,8)
    unsigned int* cnts = (unsigned int*)(ws + 8);  // [8,16): cntP, cntT

    size_t startFB = (size_t)SSF * 4;
    size_t startCB = (size_t)SS2 * 4;
    size_t needGrid = 64 + 2 * startFB + 2 * startCB + 2ull * CCF * 4
                    + 2ull * CC2 * 4 + 4ull * n * 16 + 4ull * n * 4
                    + 2ull * NCHF * 4 + 2ull * NCH2 * 4;

    if (ws_size >= needGrid && n == 131072) {
        char* p = ws + 64;
        unsigned int* startF = (unsigned int*)p;   p += 2 * startFB;
        unsigned int* startC = (unsigned int*)p;   p += 2 * startCB;
        unsigned int* nextF = (unsigned int*)p;    p += 2ull * CCF * 4;
        unsigned int* nextC = (unsigned int*)p;    p += 2ull * CC2 * 4;
        float4* sortedF = (float4*)p;              p += 2ull * n * 16;
        float4* sortedC = (float4*)p;              p += 2ull * n * 16;
        unsigned int* wlPT = (unsigned int*)p;     p += 2ull * n * 4;
        unsigned int* wbPT = (unsigned int*)p;     p += 2ull * n * 4;
        unsigned int* bsF = (unsigned int*)p;      p += 2ull * NCHF * 4;
        unsigned int* bsC = (unsigned int*)p;

        hipMemsetAsync(ws, 0, 64, stream);  // acc + cnts
        // fine counts + coarse counts are adjacent: one memset
        hipMemsetAsync(nextF, 0, 2ull * CCF * 4 + 2ull * CC2 * 4, stream);
        hist2_kernel<<<dim3(nblk, 2), 256, 0, stream>>>(pred, targ, nextF, nextC, n);
        scan_chunk_all_kernel<<<2 * NCHF + 2 * NCH2, 256, 0, stream>>>(
            nextF, startF, bsF, nextC, startC, bsC);
        scan_sums_all_kernel<<<4, 256, 0, stream>>>(bsF, bsC);
        add_offsets_all_kernel<<<2 * NCHF + 2 * NCH2, 256, 0, stream>>>(
            startF, nextF, bsF, startC, nextC, bsC, n);
        scatter_all_kernel<<<dim3(nblk, 2), 256, 0, stream>>>(
            pred, targ, nextF, nextC, sortedF, sortedC, n);

        nn_pass1_kernel<<<dim3(nblk, 2), 256, 0, stream>>>(
            sortedF, startF, n, wlPT, wbPT, cnts, acc);
        nn_pass2_kernel<<<dim3(512, 2), 256, 0, stream>>>(
            sortedF, sortedC, startC, n, wlPT, wbPT, cnts, acc);
    } else {
        hipMemsetAsync(acc, 0, sizeof(double), stream);
        size_t needBF = 64 + 2ull * n * sizeof(float4) + 2ull * n * sizeof(unsigned int);
        if (ws_size >= needBF && (n % (256 * PTS)) == 0 && (n % SPLIT) == 0) {
            float4* P = (float4*)(ws + 64);
            float4* T = P + n;
            unsigned int* minPT = (unsigned int*)(T + n);
            pack_kernel<<<nblk, 256, 0, stream>>>(pred, P, n);
            pack_kernel<<<nblk, 256, 0, stream>>>(targ, T, n);
            hipMemsetAsync(minPT, 0xFF, 2ull * n * sizeof(unsigned int), stream);
            dim3 grid(n / (256 * PTS), SPLIT);
            chamfer_dir_kernel<<<grid, 256, 0, stream>>>(P, T, n, minPT);
            chamfer_dir_kernel<<<grid, 256, 0, stream>>>(T, P, n, minPT + n);
            reduce_kernel<<<256, 256, 0, stream>>>(minPT, 2 * n, acc);
        }
    }
    finalize_kernel<<<1, 1, 0, stream>>>(acc, out, n);
}